// Round 1
// baseline (419.393 us; speedup 1.0000x reference)
//
#include <hip/hip_runtime.h>

#define NIMG 16
#define NC 3
#define H 256
#define W 256
#define HW (H * W)
#define NS 25          // 5x5 per-pixel kernel
#define TH 32
#define TW 32
#define SRH (TH + 10)  // s-tile region: fac halo(2) + conv halo(3) each side
#define SRW (TW + 10)
#define SRN (SRH * SRW)            // 1764
#define MRH (TH + 4)   // q region: fac halo(2) each side
#define MRW (TW + 4)
#define MRN (MRH * MRW)            // 1296
#define NTHREADS 256
#define PPT ((TH * TW) / NTHREADS) // 4
#define RPT ((SRN + NTHREADS - 1) / NTHREADS)  // 7 region points per thread

// round-to-nearest-even fp32 -> bf16 (as u16)
__device__ __forceinline__ unsigned bf16r(float x) {
    union { float f; unsigned u; } c; c.f = x;
    return (c.u + 0x7FFFu + ((c.u >> 16) & 1u)) >> 16;
}
__device__ __forceinline__ float bf_hi(unsigned u) {  // high 16 bits -> float
    union { unsigned u; float f; } c; c.u = u & 0xFFFF0000u; return c.f;
}
__device__ __forceinline__ float bf_lo(unsigned u) {  // low 16 bits -> float
    union { unsigned u; float f; } c; c.u = u << 16; return c.f;
}

// Single fused kernel: per 32x32 tile, for each branch b:
//   phase 1: stream perpix_b over the 42x42 halo region, reduce (sum,max)
//            over 25 channels into registers, pack bf16 pair -> LDS s_l.
//            (HBM sees ~1x compulsory traffic: cross-block halo overlap is
//             absorbed by L3; the old A->B split paid 2x because three
//             streamed tensors (315 MB) thrash the 256 MB L3.)
//   phase 2: conv7x7(s)+sigmoid -> mask; q = mask*blur (3 ch) in LDS.
//   phase 3: per-pixel 5x5 fac; accumulate into 12 out registers.
// Epilogue: out = blur + (sum_b f_b)/3, single write, no RMW round trips.
__global__ __launch_bounds__(NTHREADS, 4)
void reblur_fused(const float* __restrict__ blur_info,
                  const float* __restrict__ pp0,
                  const float* __restrict__ pp1,
                  const float* __restrict__ pp2,
                  const float* __restrict__ wt0,
                  const float* __restrict__ wt1,
                  const float* __restrict__ wt2,
                  float* __restrict__ out)
{
    __shared__ unsigned s_l[SRN];        // 7.1 KB packed (sum,max) bf16 pair
    __shared__ float q[NC][MRN];         // 15.6 KB  q = mask*blur
    __shared__ float wts[3][98];         // 1.2 KB, all branch conv weights

    const int tid = threadIdx.x;
    const int n  = blockIdx.z;
    const int h0 = blockIdx.y * TH;
    const int w0 = blockIdx.x * TW;

    // all 3 branches' weights, 1/25 mean factor folded into avg-channel taps
    if (tid < 98) {
        float sc = (tid < 49) ? 0.04f : 1.0f;
        wts[0][tid] = wt0[tid] * sc;
        wts[1][tid] = wt1[tid] * sc;
        wts[2][tid] = wt2[tid] * sc;
    }

    // precompute the 7 halo-region points this thread owns (static arrays)
    int off[RPT]; bool val[RPT];
    #pragma unroll
    for (int r = 0; r < RPT; ++r) {
        int rp = tid + r * NTHREADS;
        int rr = rp / SRW, cc = rp % SRW;
        int gh = h0 - 5 + rr, gw = w0 - 5 + cc;
        val[r] = (rp < SRN) && ((unsigned)gh < H) && ((unsigned)gw < W);
        off[r] = gh * W + gw;
    }

    float facc0[PPT], facc1[PPT], facc2[PPT];
    #pragma unroll
    for (int k = 0; k < PPT; ++k) { facc0[k] = 0.f; facc1[k] = 0.f; facc2[k] = 0.f; }

    const size_t nbase = (size_t)n * NS * HW;

    #pragma unroll 1
    for (int b = 0; b < 3; ++b) {
        const float* pb = (b == 0) ? pp0 : ((b == 1) ? pp1 : pp2);
        pb += nbase;

        // ---- phase 1: stream 42x42x25 region, reduce channels in registers
        float sm[RPT], mx[RPT];
        #pragma unroll
        for (int r = 0; r < RPT; ++r) { sm[r] = 0.f; mx[r] = -3.0e38f; }
        #pragma unroll 5
        for (int s = 0; s < NS; ++s) {
            const float* pl = pb + s * HW;
            #pragma unroll
            for (int r = 0; r < RPT; ++r) {
                float v = val[r] ? pl[off[r]] : 0.f;
                sm[r] += v;
                mx[r] = fmaxf(mx[r], v);
            }
        }
        #pragma unroll
        for (int r = 0; r < RPT; ++r) {
            int rp = tid + r * NTHREADS;
            if (rp < SRN)
                s_l[rp] = val[r] ? ((bf16r(sm[r]) << 16) | bf16r(mx[r])) : 0u;
        }
        __syncthreads();

        // ---- phase 2: conv7x7 + sigmoid -> q = mask*blur over 36x36
        const float* wb = &wts[b][0];
        for (int i = tid; i < MRN; i += NTHREADS) {
            int rr = i / MRW, cc = i % MRW;
            float a = 0.f;
            #pragma unroll
            for (int j = 0; j < 7; ++j) {
                #pragma unroll
                for (int t = 0; t < 7; ++t) {
                    unsigned u = s_l[(rr + j) * SRW + cc + t];
                    a += bf_hi(u) * wb[j * 7 + t] + bf_lo(u) * wb[49 + j * 7 + t];
                }
            }
            float m = 1.f / (1.f + __expf(-a));
            int gh = h0 - 2 + rr, gw = w0 - 2 + cc;
            bool inb = (unsigned)gh < H && (unsigned)gw < W;
            int gi = gh * W + gw;
            #pragma unroll
            for (int c = 0; c < NC; ++c) {
                float bv = inb ? blur_info[(n * NC + c) * HW + gi] : 0.f;  // feat zero-pad
                q[c][i] = m * bv;
            }
        }
        __syncthreads();

        // ---- phase 3: fac, accumulate f_b = -q_center + sum_s pk_s * q_s
        // pk center reads hit L2/L3: this block streamed them microseconds ago.
        #pragma unroll
        for (int k = 0; k < PPT; ++k) {
            int oi = tid + k * NTHREADS;
            int r = oi / TW, cc = oi % TW;
            const float* pk = pb + (h0 + r) * W + (w0 + cc);
            int qc = (r + 2) * MRW + cc + 2;
            float f0 = -q[0][qc], f1 = -q[1][qc], f2 = -q[2][qc];
            #pragma unroll
            for (int s = 0; s < NS; ++s) {
                int qi = (r + s / 5) * MRW + cc + (s % 5);
                float v = pk[s * HW];
                f0 += v * q[0][qi];
                f1 += v * q[1][qi];
                f2 += v * q[2][qi];
            }
            facc0[k] += f0; facc1[k] += f1; facc2[k] += f2;
        }
        // next iteration's phase-1 s_l overwrite is safe: all phase-2 s_l reads
        // completed before the post-phase-2 barrier; q overwrite is fenced by
        // the post-phase-1 barrier of the next branch.
    }

    // ---- epilogue: out = blur + (f_1+f_2+f_3)/3   (blur*(1-m) folded in via -q_center)
    const float inv3 = 1.f / 3.f;
    #pragma unroll
    for (int k = 0; k < PPT; ++k) {
        int oi = tid + k * NTHREADS;
        int r = oi / TW, cc = oi % TW;
        int gi = (h0 + r) * W + (w0 + cc);
        out[(n * NC + 0) * HW + gi] = blur_info[(n * NC + 0) * HW + gi] + facc0[k] * inv3;
        out[(n * NC + 1) * HW + gi] = blur_info[(n * NC + 1) * HW + gi] + facc1[k] * inv3;
        out[(n * NC + 2) * HW + gi] = blur_info[(n * NC + 2) * HW + gi] + facc2[k] * inv3;
    }
}

extern "C" void kernel_launch(void* const* d_in, const int* in_sizes, int n_in,
                              void* d_out, int out_size, void* d_ws, size_t ws_size,
                              hipStream_t stream) {
    const float* blur = (const float*)d_in[0];
    float* out = (float*)d_out;

    dim3 grid(W / TW, H / TH, NIMG);     // 8 x 8 x 16 = 1024 blocks = 4/CU
    reblur_fused<<<grid, NTHREADS, 0, stream>>>(
        blur,
        (const float*)d_in[1], (const float*)d_in[2], (const float*)d_in[3],
        (const float*)d_in[4], (const float*)d_in[5], (const float*)d_in[6],
        out);
}

// Round 2
// 375.633 us; speedup vs baseline: 1.1165x; 1.1165x over previous
//
#include <hip/hip_runtime.h>

#define NIMG 16
#define NC 3
#define H 256
#define W 256
#define HW (H * W)
#define NS 25          // 5x5 per-pixel kernel
#define TH 32
#define TW 32
#define SRH (TH + 10)  // s-tile region: fac halo(2) + conv halo(3) each side
#define SRW (TW + 10)
#define SRN (SRH * SRW)            // 1764
#define MRH (TH + 4)   // q region: fac halo(2) each side
#define MRW (TW + 4)
#define MRN (MRH * MRW)            // 1296
#define NTHREADS 256
#define PPT ((TH * TW) / NTHREADS) // 4 center pixels per thread
#define NHALO (SRN - TH * TW)      // 740 halo-only region points

// round-to-nearest-even fp32 -> bf16 (as u16)
__device__ __forceinline__ unsigned bf16r(float x) {
    union { float f; unsigned u; } c; c.f = x;
    return (c.u + 0x7FFFu + ((c.u >> 16) & 1u)) >> 16;
}
__device__ __forceinline__ float bf_hi(unsigned u) {  // high 16 bits -> float
    union { unsigned u; float f; } c; c.u = u & 0xFFFF0000u; return c.f;
}
__device__ __forceinline__ float bf_lo(unsigned u) {  // low 16 bits -> float
    union { unsigned u; float f; } c; c.u = u << 16; return c.f;
}

// Fused kernel, v2.
//  - Ownership: thread owns center pixels {tid + k*256}. During phase-1
//    streaming it KEEPS all 25 channel values of its 4 pixels in registers
//    (statically indexed -> VGPRs, ~100 regs), so phase-3 fac does ZERO
//    global loads. This removes the 315 MB phase-3 perpix refetch that
//    rocprof showed (697 MB fetched vs 340 MB compulsory).
//  - XCD-chunked blockIdx swizzle: hw dispatch id i -> tile (i%8)*128+i/8,
//    so each XCD's L2 holds 2 contiguous images; tile-halo overlap and the
//    3x blur re-reads become L2 hits instead of fabric refetches.
//  - launch_bounds(256,2): allow ~200 VGPR, 2 waves/SIMD. Phase-1 has
//    25-deep independent-load ILP per pixel, enough MLP at 8 waves/CU.
__global__ __launch_bounds__(NTHREADS, 2)
void reblur_fused(const float* __restrict__ blur_info,
                  const float* __restrict__ pp0,
                  const float* __restrict__ pp1,
                  const float* __restrict__ pp2,
                  const float* __restrict__ wt0,
                  const float* __restrict__ wt1,
                  const float* __restrict__ wt2,
                  float* __restrict__ out)
{
    __shared__ unsigned s_l[SRN];        // 7.1 KB packed (sum,max) bf16 pair
    __shared__ float q[NC][MRN];         // 15.6 KB  q = mask*blur
    __shared__ float wts[3][98];         // 1.2 KB, all branch conv weights

    const int tid = threadIdx.x;

    // XCD-chunked swizzle (bijective: 1024 % 8 == 0). hw id -> assigned tile.
    const int id  = blockIdx.x + (blockIdx.y << 3) + (blockIdx.z << 6);
    const int sid = ((id & 7) << 7) + (id >> 3);
    const int n   = sid >> 6;
    const int h0  = ((sid >> 3) & 7) * TH;
    const int w0  = (sid & 7) * TW;

    // all 3 branches' weights, 1/25 mean factor folded into avg-channel taps
    if (tid < 98) {
        float sc = (tid < 49) ? 0.04f : 1.0f;
        wts[0][tid] = wt0[tid] * sc;
        wts[1][tid] = wt1[tid] * sc;
        wts[2][tid] = wt2[tid] * sc;
    }

    float facc0[PPT], facc1[PPT], facc2[PPT];
    #pragma unroll
    for (int k = 0; k < PPT; ++k) { facc0[k] = 0.f; facc1[k] = 0.f; facc2[k] = 0.f; }

    const size_t nbase = (size_t)n * NS * HW;

    float pk[PPT][NS];   // statically indexed only -> stays in VGPRs

    #pragma unroll 1
    for (int b = 0; b < 3; ++b) {
        const float* pb = (b == 0) ? pp0 : ((b == 1) ? pp1 : pp2);
        pb += nbase;

        // ---- phase 1a: center 32x32 — stream 25 ch, reduce AND keep in regs
        #pragma unroll
        for (int k = 0; k < PPT; ++k) {
            const int oi = tid + k * NTHREADS;
            const int r = oi >> 5, c = oi & 31;
            const float* p = pb + (h0 + r) * W + (w0 + c);
            float v = p[0];
            pk[k][0] = v;
            float sm = v, mx = v;
            #pragma unroll
            for (int s = 1; s < NS; ++s) {
                v = p[s * HW];
                pk[k][s] = v;
                sm += v; mx = fmaxf(mx, v);
            }
            s_l[(r + 5) * SRW + (c + 5)] = (bf16r(sm) << 16) | bf16r(mx);
        }

        // ---- phase 1b: halo-only points (740) — reduce, no storage
        for (int m = tid; m < NHALO; m += NTHREADS) {
            int rr, cc;
            if (m < 210)      { rr = m / 42;              cc = m % 42; }
            else if (m < 420) { int t = m - 210; rr = 37 + t / 42; cc = t % 42; }
            else              { int t = m - 420; rr = 5 + t / 10;
                                int c2 = t % 10; cc = (c2 < 5) ? c2 : c2 + 32; }
            const int gh = h0 - 5 + rr, gw = w0 - 5 + cc;
            unsigned u = 0;
            if ((unsigned)gh < H && (unsigned)gw < W) {
                const float* p = pb + gh * W + gw;
                float v = p[0];
                float sm = v, mx = v;
                #pragma unroll
                for (int s = 1; s < NS; ++s) {
                    v = p[s * HW];
                    sm += v; mx = fmaxf(mx, v);
                }
                u = (bf16r(sm) << 16) | bf16r(mx);
            }
            s_l[rr * SRW + cc] = u;
        }
        __syncthreads();

        // ---- phase 2: conv7x7 + sigmoid -> q = mask*blur over 36x36
        const float* wb = &wts[b][0];
        for (int i = tid; i < MRN; i += NTHREADS) {
            int rr = i / MRW, cc = i % MRW;
            float a = 0.f;
            #pragma unroll
            for (int j = 0; j < 7; ++j) {
                #pragma unroll
                for (int t = 0; t < 7; ++t) {
                    unsigned u = s_l[(rr + j) * SRW + cc + t];
                    a += bf_hi(u) * wb[j * 7 + t] + bf_lo(u) * wb[49 + j * 7 + t];
                }
            }
            float m = 1.f / (1.f + __expf(-a));
            int gh = h0 - 2 + rr, gw = w0 - 2 + cc;
            bool inb = (unsigned)gh < H && (unsigned)gw < W;
            int gi = gh * W + gw;
            #pragma unroll
            for (int c = 0; c < NC; ++c) {
                float bv = inb ? blur_info[(n * NC + c) * HW + gi] : 0.f;  // feat zero-pad
                q[c][i] = m * bv;
            }
        }
        __syncthreads();

        // ---- phase 3: fac from REGISTERS — zero global traffic
        #pragma unroll
        for (int k = 0; k < PPT; ++k) {
            const int oi = tid + k * NTHREADS;
            const int r = oi >> 5, c = oi & 31;
            const int qc = (r + 2) * MRW + c + 2;
            float f0 = -q[0][qc], f1 = -q[1][qc], f2 = -q[2][qc];
            #pragma unroll
            for (int s = 0; s < NS; ++s) {
                const int qi = (r + s / 5) * MRW + c + (s % 5);
                const float v = pk[k][s];
                f0 += v * q[0][qi];
                f1 += v * q[1][qi];
                f2 += v * q[2][qi];
            }
            facc0[k] += f0; facc1[k] += f1; facc2[k] += f2;
        }
        // next branch's phase-1 writes s_l (not read by phase 3) and is
        // followed by a barrier before phase 2 overwrites q -> race-free.
    }

    // ---- epilogue: out = blur + (f_1+f_2+f_3)/3  (blur*(1-m) folded via -q_center)
    const float inv3 = 1.f / 3.f;
    #pragma unroll
    for (int k = 0; k < PPT; ++k) {
        const int oi = tid + k * NTHREADS;
        const int r = oi >> 5, c = oi & 31;
        const int gi = (h0 + r) * W + (w0 + c);
        out[(n * NC + 0) * HW + gi] = blur_info[(n * NC + 0) * HW + gi] + facc0[k] * inv3;
        out[(n * NC + 1) * HW + gi] = blur_info[(n * NC + 1) * HW + gi] + facc1[k] * inv3;
        out[(n * NC + 2) * HW + gi] = blur_info[(n * NC + 2) * HW + gi] + facc2[k] * inv3;
    }
}

extern "C" void kernel_launch(void* const* d_in, const int* in_sizes, int n_in,
                              void* d_out, int out_size, void* d_ws, size_t ws_size,
                              hipStream_t stream) {
    const float* blur = (const float*)d_in[0];
    float* out = (float*)d_out;

    dim3 grid(W / TW, H / TH, NIMG);     // 8 x 8 x 16 = 1024 blocks
    reblur_fused<<<grid, NTHREADS, 0, stream>>>(
        blur,
        (const float*)d_in[1], (const float*)d_in[2], (const float*)d_in[3],
        (const float*)d_in[4], (const float*)d_in[5], (const float*)d_in[6],
        out);
}